// Round 1
// baseline (968.383 us; speedup 1.0000x reference)
//
#include <hip/hip_runtime.h>
#include <hip/hip_bf16.h>

#define Bn 64
#define Tn 512
#define En 128
#define Hn 64
#define Gn 256   // 4*H
#define Cn 20

__device__ __forceinline__ float sigf(float x)      { return 1.f/(1.f+__expf(-x)); }
__device__ __forceinline__ float tanhfast(float x)  { return 2.f/(1.f+__expf(-2.f*x)) - 1.f; }

// ---------------------------------------------------------------------------
// Kernel A: Z0[b*T+t][j] = (word_emb[ids[b,t]] + pos_emb[t]) @ Wx_b0 + b_b0
// grid = (B*T)/64 blocks, 256 threads. 64 rows x 256 cols per block.
// ---------------------------------------------------------------------------
__global__ __launch_bounds__(256, 1) void emb_proj_kernel(
    const int* __restrict__ x, const float* __restrict__ word_emb,
    const float* __restrict__ pos_emb, const float* __restrict__ wx,
    const float* __restrict__ bias, float* __restrict__ z0)
{
  __shared__ float emb[64][En];     // 32 KB
  __shared__ float wxl[32][Gn];     // 32 KB (K-chunk of Wx)
  const int tid  = threadIdx.x;
  const int row0 = blockIdx.x * 64;

  // stage 64 embedding rows into LDS (float4, coalesced)
  #pragma unroll
  for (int it = 0; it < 8; ++it) {
    int idx = it*256 + tid;           // 0..2047
    int rr  = idx >> 5;               // row within tile
    int e4  = (idx & 31) << 2;        // float4 offset within row
    int r   = row0 + rr;
    int b   = r >> 9;                 // r / T
    int t   = r & (Tn-1);             // r % T
    int id  = x[b*3*Tn + t];          // ids channel
    float4 we = *reinterpret_cast<const float4*>(&word_emb[(size_t)id*En + e4]);
    float4 pe = *reinterpret_cast<const float4*>(&pos_emb[(size_t)t*En + e4]);
    float4 v  = make_float4(we.x+pe.x, we.y+pe.y, we.z+pe.z, we.w+pe.w);
    *reinterpret_cast<float4*>(&emb[rr][e4]) = v;
  }

  const int jc = tid & 63;      // column group -> cols jc*4 .. jc*4+3
  const int rg = tid >> 6;      // wave id -> rows rg*16 .. rg*16+15
  float acc[16][4];
  float4 bb = *reinterpret_cast<const float4*>(&bias[jc*4]);
  #pragma unroll
  for (int r = 0; r < 16; ++r) { acc[r][0]=bb.x; acc[r][1]=bb.y; acc[r][2]=bb.z; acc[r][3]=bb.w; }

  for (int ec = 0; ec < 4; ++ec) {
    __syncthreads();
    #pragma unroll
    for (int it = 0; it < 8; ++it) {
      int idx = it*256 + tid;
      int ee  = idx >> 6;
      int j4  = (idx & 63) << 2;
      *reinterpret_cast<float4*>(&wxl[ee][j4]) =
          *reinterpret_cast<const float4*>(&wx[(size_t)(ec*32+ee)*Gn + j4]);
    }
    __syncthreads();
    for (int ee = 0; ee < 32; ++ee) {
      float4 w = *reinterpret_cast<const float4*>(&wxl[ee][jc*4]);
      #pragma unroll
      for (int r = 0; r < 16; ++r) {
        float xv = emb[rg*16+r][ec*32+ee];   // wave-uniform -> LDS broadcast
        acc[r][0] = fmaf(xv, w.x, acc[r][0]);
        acc[r][1] = fmaf(xv, w.y, acc[r][1]);
        acc[r][2] = fmaf(xv, w.z, acc[r][2]);
        acc[r][3] = fmaf(xv, w.w, acc[r][3]);
      }
    }
  }
  #pragma unroll
  for (int r = 0; r < 16; ++r) {
    size_t row = (size_t)row0 + rg*16 + r;
    *reinterpret_cast<float4*>(&z0[row*Gn + jc*4]) =
        make_float4(acc[r][0], acc[r][1], acc[r][2], acc[r][3]);
  }
}

// ---------------------------------------------------------------------------
// Kernel B: layer b0 recurrence, reverse time. One block per batch element.
// thread j (0..255) owns output column j of z; threads 0..63 own gate lane j.
// Stores hb0[b][t][:] = h-state after processing original timestep t.
// ---------------------------------------------------------------------------
__global__ __launch_bounds__(256, 1) void lstm_b0_kernel(
    const int* __restrict__ x, const float* __restrict__ z0,
    const float* __restrict__ wh, float* __restrict__ hb0)
{
  const int b = blockIdx.x;
  const int j = threadIdx.x;
  __shared__ __align__(16) float h_lds[Hn];
  __shared__ float z_lds[Gn];
  __shared__ int   msk[Tn];

  float whcol[Hn];
  #pragma unroll
  for (int k = 0; k < Hn; ++k) whcol[k] = wh[k*Gn + j];
  for (int it = j; it < Tn; it += 256) msk[it] = x[b*3*Tn + 2*Tn + it];
  if (j < Hn) h_lds[j] = 0.f;
  float c = 0.f, h = 0.f;

  const float* zrow = z0 + (size_t)b*Tn*Gn;
  // software pipeline depth 3 over the reversed row stream
  float zp0 = zrow[(size_t)511*Gn + j];
  float zp1 = zrow[(size_t)510*Gn + j];
  float zp2 = zrow[(size_t)509*Gn + j];
  __syncthreads();

  for (int s = 0; s < Tn; ++s) {
    const int t = Tn-1-s;
    float a0 = zp0, a1 = 0.f, a2 = 0.f, a3 = 0.f;
    zp0 = zp1; zp1 = zp2;
    if (t >= 3) zp2 = zrow[(size_t)(t-3)*Gn + j];
    #pragma unroll
    for (int k4 = 0; k4 < 16; ++k4) {
      float4 hv = *reinterpret_cast<const float4*>(&h_lds[k4*4]);
      a0 = fmaf(hv.x, whcol[k4*4+0], a0);
      a1 = fmaf(hv.y, whcol[k4*4+1], a1);
      a2 = fmaf(hv.z, whcol[k4*4+2], a2);
      a3 = fmaf(hv.w, whcol[k4*4+3], a3);
    }
    z_lds[j] = (a0+a1)+(a2+a3);
    __syncthreads();
    if (j < Hn) {
      if (msk[t]) {
        float ig = sigf(z_lds[j]);
        float fg = sigf(z_lds[Hn+j]);
        float gg = tanhfast(z_lds[2*Hn+j]);
        float og = sigf(z_lds[3*Hn+j]);
        c = fmaf(fg, c, ig*gg);
        h = og * tanhfast(c);
      }
      h_lds[j] = h;
      hb0[((size_t)b*Tn + t)*Hn + j] = h;
    }
    __syncthreads();
  }
}

// ---------------------------------------------------------------------------
// Kernel C: layer b1 recurrence (original time order, mask index T-1-t) + head.
// One block per batch. Only the final carry h is needed -> logits -> softmax.
// ---------------------------------------------------------------------------
__global__ __launch_bounds__(256, 1) void lstm_b1_head_kernel(
    const int* __restrict__ x, const float* __restrict__ hb0,
    const float* __restrict__ wx, const float* __restrict__ wh,
    const float* __restrict__ bias, const float* __restrict__ dw,
    const float* __restrict__ db, float* __restrict__ out)
{
  const int b = blockIdx.x;
  const int j = threadIdx.x;
  __shared__ __align__(16) float xb[2][Hn];
  __shared__ __align__(16) float h_lds[Hn];
  __shared__ float z_lds[Gn];
  __shared__ int   msk[Tn];

  float wxcol[Hn], whcol[Hn];
  #pragma unroll
  for (int k = 0; k < Hn; ++k) wxcol[k] = wx[k*Gn + j];
  #pragma unroll
  for (int k = 0; k < Hn; ++k) whcol[k] = wh[k*Gn + j];
  const float bj = bias[j];
  for (int it = j; it < Tn; it += 256) msk[it] = x[b*3*Tn + 2*Tn + it];
  float c = 0.f, h = 0.f;
  const float* hrow = hb0 + (size_t)b*Tn*Hn;
  float pf1 = 0.f, pf2 = 0.f;
  if (j < Hn) {
    h_lds[j] = 0.f;
    xb[0][j] = hrow[j];
    pf1 = hrow[Hn   + j];
    pf2 = hrow[2*Hn + j];
  }
  __syncthreads();

  for (int t = 0; t < Tn; ++t) {
    float a0 = bj, a1 = 0.f, a2 = 0.f, a3 = 0.f;
    const float* xrow = xb[t & 1];
    #pragma unroll
    for (int k4 = 0; k4 < 16; ++k4) {
      float4 xv = *reinterpret_cast<const float4*>(&xrow[k4*4]);
      a0 = fmaf(xv.x, wxcol[k4*4+0], a0);
      a1 = fmaf(xv.y, wxcol[k4*4+1], a1);
      a2 = fmaf(xv.z, wxcol[k4*4+2], a2);
      a3 = fmaf(xv.w, wxcol[k4*4+3], a3);
    }
    #pragma unroll
    for (int k4 = 0; k4 < 16; ++k4) {
      float4 hv = *reinterpret_cast<const float4*>(&h_lds[k4*4]);
      a0 = fmaf(hv.x, whcol[k4*4+0], a0);
      a1 = fmaf(hv.y, whcol[k4*4+1], a1);
      a2 = fmaf(hv.z, whcol[k4*4+2], a2);
      a3 = fmaf(hv.w, whcol[k4*4+3], a3);
    }
    z_lds[j] = (a0+a1)+(a2+a3);
    // double-buffered x prefetch: write row t+1, issue load for row t+3
    if (j < Hn) {
      if (t+1 < Tn) xb[(t+1)&1][j] = pf1;
      pf1 = pf2;
      if (t+3 < Tn) pf2 = hrow[(size_t)(t+3)*Hn + j];
    }
    __syncthreads();
    if (j < Hn) {
      if (msk[Tn-1-t]) {         // note: mask misaligned by reference's double flip
        float ig = sigf(z_lds[j]);
        float fg = sigf(z_lds[Hn+j]);
        float gg = tanhfast(z_lds[2*Hn+j]);
        float og = sigf(z_lds[3*Hn+j]);
        c = fmaf(fg, c, ig*gg);
        h = og * tanhfast(c);
      }
      h_lds[j] = h;
    }
    __syncthreads();
  }

  // head: logits (C=20) + softmax
  if (j < Cn) {
    float lg = db[j];
    #pragma unroll
    for (int k = 0; k < Hn; ++k) lg = fmaf(h_lds[k], dw[k*Cn + j], lg);
    z_lds[j] = lg;
  }
  __syncthreads();
  if (j < Cn) {
    float m = z_lds[0];
    #pragma unroll
    for (int k = 1; k < Cn; ++k) m = fmaxf(m, z_lds[k]);
    z_lds[32 + j] = __expf(z_lds[j] - m);
  }
  __syncthreads();
  if (j < Cn) {
    float ssum = 0.f;
    #pragma unroll
    for (int k = 0; k < Cn; ++k) ssum += z_lds[32 + k];
    out[b*Cn + j] = z_lds[32 + j] / ssum;
  }
}

// ---------------------------------------------------------------------------
extern "C" void kernel_launch(void* const* d_in, const int* in_sizes, int n_in,
                              void* d_out, int out_size, void* d_ws, size_t ws_size,
                              hipStream_t stream)
{
  const int*   x        = (const int*)  d_in[0];
  const float* word_emb = (const float*)d_in[1];
  const float* pos_emb  = (const float*)d_in[2];
  // forward-branch weights d_in[3..8] are dead code in the reference
  const float* wx_b0    = (const float*)d_in[9];
  const float* wh_b0    = (const float*)d_in[10];
  const float* b_b0     = (const float*)d_in[11];
  const float* wx_b1    = (const float*)d_in[12];
  const float* wh_b1    = (const float*)d_in[13];
  const float* b_b1     = (const float*)d_in[14];
  const float* dw       = (const float*)d_in[15];
  const float* db       = (const float*)d_in[16];
  float* out = (float*)d_out;

  float* z0  = (float*)d_ws;                    // B*T*256 f32 = 33.5 MB
  float* hb0 = z0 + (size_t)Bn*Tn*Gn;           // B*T*64  f32 =  8.4 MB

  emb_proj_kernel<<<dim3((Bn*Tn)/64), dim3(256), 0, stream>>>(
      x, word_emb, pos_emb, wx_b0, b_b0, z0);
  lstm_b0_kernel<<<dim3(Bn), dim3(256), 0, stream>>>(x, z0, wh_b0, hb0);
  lstm_b1_head_kernel<<<dim3(Bn), dim3(256), 0, stream>>>(
      x, hb0, wx_b1, wh_b1, b_b1, dw, db, out);
}